// Round 1
// baseline (261.481 us; speedup 1.0000x reference)
//
#include <hip/hip_runtime.h>
#include <stdint.h>

// Fused attention: q/k/v projections + softmax(QK^T/32 + mask) @ V
// B=4, S=2048, E=1024. All GEMMs are NT bf16 MFMA (16x16x32), m97-style
// 128x128 tile, BK=64, 4 waves, global_load_lds(16B) staging.
//
// ws layout (MB offsets):
//   0: qb bf16[4][2048][1024]      16MB
//  16: kb bf16[4][2048][1024]      16MB
//  32: vT bf16[4][1024][2048]      16MB  (v projected transposed)
//  48: Sb bf16[4][2048][2048]      32MB  (scores -> in-place softmax P)
//  80: xq bf16                     16MB  (converted query)
//  96: xk bf16                     16MB
// 112: xv bf16                     16MB
// 128/130/132: Wqb/Wkb/Wvb bf16     6MB
// total 134MB

typedef __attribute__((ext_vector_type(8))) short s8v;    // 8 bf16 bit patterns
typedef __attribute__((ext_vector_type(4))) float f32x4;

__device__ __forceinline__ unsigned short f2b(float f) {
  union { float f; unsigned u; } c; c.f = f;
  unsigned r = c.u + 0x7fffu + ((c.u >> 16) & 1u);   // RNE, no NaN inputs
  return (unsigned short)(r >> 16);
}
__device__ __forceinline__ float b2f(unsigned short s) {
  union { float f; unsigned u; } c; c.u = ((unsigned)s) << 16; return c.f;
}

// global -> LDS direct copy, 16B per lane. LDS dest must be wave-uniform;
// HW writes at ldsbase + lane*16. Casts via integer round-trip (CK pattern).
__device__ __forceinline__ void gload_lds16(const void* gsrc, void* ldst) {
  __builtin_amdgcn_global_load_lds(
      (__attribute__((address_space(1))) unsigned int*)(uintptr_t)gsrc,
      (__attribute__((address_space(3))) unsigned int*)(unsigned)(uintptr_t)ldst,
      16, 0, 0);
}

// NT GEMM: C[m][n] = scale * sum_k A[m][k]*B[n][k]  (+ bias / + mask)
// A,B bf16 (ushort bits). C bf16 or f32. M,N mult of 128; K mult of 64.
// BIAS: 0 none, 1 bias[col], 2 bias[row]. MASK: add f32 mask[row][col].
template <bool OUT_BF16, int BIAS, bool MASK>
__global__ __launch_bounds__(256, 2) void gemm_nt(
    const unsigned short* __restrict__ A, long strideAb, int lda,
    const unsigned short* __restrict__ B, long strideBb, int ldb,
    void* __restrict__ Cptr, long strideCb, int ldc,
    const float* __restrict__ bias,
    const float* __restrict__ maskp, long strideMb, int ldM,
    int M, int N, int K, float scale, int tilesN) {
  __shared__ __align__(16) short AsS[128 * 64];
  __shared__ __align__(16) short BsS[128 * 64];

  const int tid = threadIdx.x;
  const int lane = tid & 63;
  const int w = tid >> 6;            // wave 0..3
  const int wr = w >> 1, wc = w & 1; // 2x2 wave grid, 64x64 out each
  const int batch = blockIdx.y;
  const int tm = blockIdx.x / tilesN, tn = blockIdx.x % tilesN;
  const int brow = tm * 128, bcol = tn * 128;

  // staging: each wave stages 4 chunks of A and B; chunk = 8 rows x 64 cols
  const unsigned short* aSrc = A + (long)batch * strideAb +
      (long)(brow + w * 32 + (lane >> 3)) * lda + (lane & 7) * 8;
  const unsigned short* bSrc = B + (long)batch * strideBb +
      (long)(bcol + w * 32 + (lane >> 3)) * ldb + (lane & 7) * 8;

  f32x4 acc[4][4];
#pragma unroll
  for (int i = 0; i < 4; i++)
#pragma unroll
    for (int j = 0; j < 4; j++) acc[i][j] = (f32x4){0.f, 0.f, 0.f, 0.f};

  const int fr = lane & 15;       // fragment row/col
  const int fq = lane >> 4;       // 0..3
  const int nk = K >> 6;

  for (int kt = 0; kt < nk; kt++) {
#pragma unroll
    for (int i = 0; i < 4; i++) {
      gload_lds16(aSrc + (long)i * 8 * lda, &AsS[w * 2048 + i * 512]);
      gload_lds16(bSrc + (long)i * 8 * ldb, &BsS[w * 2048 + i * 512]);
    }
    aSrc += 64; bSrc += 64;
    __syncthreads();   // drains vmcnt (global_load_lds) + barrier
#pragma unroll
    for (int ks = 0; ks < 2; ks++) {
      s8v af[4], bf[4];
#pragma unroll
      for (int mi = 0; mi < 4; mi++)
        af[mi] = *(const s8v*)&AsS[(wr * 64 + mi * 16 + fr) * 64 + ks * 32 + fq * 8];
#pragma unroll
      for (int ni = 0; ni < 4; ni++)
        bf[ni] = *(const s8v*)&BsS[(wc * 64 + ni * 16 + fr) * 64 + ks * 32 + fq * 8];
#pragma unroll
      for (int mi = 0; mi < 4; mi++)
#pragma unroll
        for (int ni = 0; ni < 4; ni++)
          acc[mi][ni] = __builtin_amdgcn_mfma_f32_16x16x32_bf16(
              af[mi], bf[ni], acc[mi][ni], 0, 0, 0);
    }
    __syncthreads();
  }

  // epilogue: C/D layout col=lane&15, row=(lane>>4)*4+r  [m89-verified]
  unsigned short* Cb = (unsigned short*)Cptr;
  float* Cf = (float*)Cptr;
  const long cB = (long)batch * strideCb;
  const float* maskB = MASK ? (maskp + (long)batch * strideMb) : nullptr;
#pragma unroll
  for (int mi = 0; mi < 4; mi++) {
#pragma unroll
    for (int ni = 0; ni < 4; ni++) {
      const int col = bcol + wc * 64 + ni * 16 + fr;
#pragma unroll
      for (int r = 0; r < 4; r++) {
        const int row = brow + wr * 64 + mi * 16 + fq * 4 + r;
        float v = acc[mi][ni][r] * scale;
        if (BIAS == 1) v += bias[col];
        if (BIAS == 2) v += bias[row];
        if (MASK) v += maskB[(long)row * ldM + col];
        if (OUT_BF16) Cb[cB + (long)row * ldc + col] = f2b(v);
        else          Cf[cB + (long)row * ldc + col] = v;
      }
    }
  }
}

// f32 -> bf16 elementwise, 8 elems/thread, grid-stride
__global__ __launch_bounds__(256) void cvt_f32_bf16(
    const float* __restrict__ in, unsigned short* __restrict__ out, long n8) {
  long i = (long)blockIdx.x * blockDim.x + threadIdx.x;
  const long stride = (long)gridDim.x * blockDim.x;
  for (; i < n8; i += stride) {
    const float* p = in + i * 8;
    f32x4 a = *(const f32x4*)p;
    f32x4 b = *(const f32x4*)(p + 4);
    s8v o;
    o[0] = (short)f2b(a[0]); o[1] = (short)f2b(a[1]);
    o[2] = (short)f2b(a[2]); o[3] = (short)f2b(a[3]);
    o[4] = (short)f2b(b[0]); o[5] = (short)f2b(b[1]);
    o[6] = (short)f2b(b[2]); o[7] = (short)f2b(b[3]);
    *(s8v*)(out + i * 8) = o;
  }
}

// in-place row softmax over 2048 bf16 entries; one block (4 waves) per row
__global__ __launch_bounds__(256) void softmax_inplace(unsigned short* __restrict__ S) {
  const long row = blockIdx.x;
  unsigned short* rp = S + row * 2048;
  const int tid = threadIdx.x, lane = tid & 63, wid = tid >> 6;

  s8v vb = *(const s8v*)&rp[tid * 8];
  float x[8];
#pragma unroll
  for (int j = 0; j < 8; j++) x[j] = b2f((unsigned short)vb[j]);

  float m = x[0];
#pragma unroll
  for (int j = 1; j < 8; j++) m = fmaxf(m, x[j]);
#pragma unroll
  for (int off = 32; off > 0; off >>= 1) m = fmaxf(m, __shfl_xor(m, off, 64));

  __shared__ float red[4];
  if (lane == 0) red[wid] = m;
  __syncthreads();
  m = fmaxf(fmaxf(red[0], red[1]), fmaxf(red[2], red[3]));
  __syncthreads();

  float s = 0.f;
#pragma unroll
  for (int j = 0; j < 8; j++) { x[j] = __expf(x[j] - m); s += x[j]; }
#pragma unroll
  for (int off = 32; off > 0; off >>= 1) s += __shfl_xor(s, off, 64);
  if (lane == 0) red[wid] = s;
  __syncthreads();
  s = red[0] + red[1] + red[2] + red[3];
  const float inv = 1.0f / s;

  s8v ob;
#pragma unroll
  for (int j = 0; j < 8; j++) ob[j] = (short)f2b(x[j] * inv);
  *(s8v*)&rp[tid * 8] = ob;
}

extern "C" void kernel_launch(void* const* d_in, const int* in_sizes, int n_in,
                              void* d_out, int out_size, void* d_ws, size_t ws_size,
                              hipStream_t stream) {
  const float* q    = (const float*)d_in[0];
  const float* k    = (const float*)d_in[1];
  const float* v    = (const float*)d_in[2];
  const float* mask = (const float*)d_in[3];
  const float* Wq   = (const float*)d_in[4];
  const float* bq   = (const float*)d_in[5];
  const float* Wk   = (const float*)d_in[6];
  const float* bk   = (const float*)d_in[7];
  const float* Wv   = (const float*)d_in[8];
  const float* bv   = (const float*)d_in[9];
  float* out = (float*)d_out;

  const size_t MB = 1ull << 20;
  if (ws_size < 134 * MB) return;   // fail visibly rather than corrupt
  char* ws = (char*)d_ws;
  unsigned short* qb  = (unsigned short*)(ws + 0 * MB);
  unsigned short* kb  = (unsigned short*)(ws + 16 * MB);
  unsigned short* vT  = (unsigned short*)(ws + 32 * MB);
  unsigned short* Sb  = (unsigned short*)(ws + 48 * MB);
  unsigned short* xq  = (unsigned short*)(ws + 80 * MB);
  unsigned short* xk  = (unsigned short*)(ws + 96 * MB);
  unsigned short* xv  = (unsigned short*)(ws + 112 * MB);
  unsigned short* Wqb = (unsigned short*)(ws + 128 * MB);
  unsigned short* Wkb = (unsigned short*)(ws + 130 * MB);
  unsigned short* Wvb = (unsigned short*)(ws + 132 * MB);

  const long NX = 4L * 2048 * 1024;   // 8388608
  const long NW = 1024L * 1024;

  cvt_f32_bf16<<<2048, 256, 0, stream>>>(q, xq, NX / 8);
  cvt_f32_bf16<<<2048, 256, 0, stream>>>(k, xk, NX / 8);
  cvt_f32_bf16<<<2048, 256, 0, stream>>>(v, xv, NX / 8);
  cvt_f32_bf16<<<512, 256, 0, stream>>>(Wq, Wqb, NW / 8);
  cvt_f32_bf16<<<512, 256, 0, stream>>>(Wk, Wkb, NW / 8);
  cvt_f32_bf16<<<512, 256, 0, stream>>>(Wv, Wvb, NW / 8);

  // q,k projections: C[s][f] = x[s][e] W[f][e] + b[f]; M=8192 N=1024 K=1024
  gemm_nt<true, 1, false><<<dim3(64 * 8, 1), 256, 0, stream>>>(
      xq, 0, 1024, Wqb, 0, 1024, (void*)qb, 0, 1024,
      bq, nullptr, 0, 0, 8192, 1024, 1024, 1.0f, 8);
  gemm_nt<true, 1, false><<<dim3(64 * 8, 1), 256, 0, stream>>>(
      xk, 0, 1024, Wkb, 0, 1024, (void*)kb, 0, 1024,
      bk, nullptr, 0, 0, 8192, 1024, 1024, 1.0f, 8);
  // v projected transposed: vT[f][s] = Wv[f][e] x[s][e] + bv[f]; M=1024 N=2048
  gemm_nt<true, 2, false><<<dim3(8 * 16, 4), 256, 0, stream>>>(
      Wvb, 0, 1024, xv, 2048L * 1024, 1024, (void*)vT, 1024L * 2048, 2048,
      bv, nullptr, 0, 0, 1024, 2048, 1024, 1.0f, 16);
  // scores: S[q][kk] = (qb.kb)/32 + mask; M=N=2048 K=1024, bf16 out
  gemm_nt<true, 0, true><<<dim3(16 * 16, 4), 256, 0, stream>>>(
      qb, 2048L * 1024, 1024, kb, 2048L * 1024, 1024, (void*)Sb, 2048L * 2048, 2048,
      nullptr, mask, 2048L * 2048, 2048, 2048, 2048, 1024, 0.03125f, 16);
  // softmax rows in-place (4*2048 rows)
  softmax_inplace<<<8192, 256, 0, stream>>>(Sb);
  // PV: out[q][e] = P[q][kk] vT[e][kk]; M=2048 N=1024 K=2048, f32 out
  gemm_nt<false, 0, false><<<dim3(16 * 8, 4), 256, 0, stream>>>(
      Sb, 2048L * 2048, 2048, vT, 1024L * 2048, 2048, (void*)out, 2048L * 1024, 1024,
      nullptr, nullptr, 0, 0, 2048, 1024, 2048, 1.0f, 8);
}

// Round 2
// 232.700 us; speedup vs baseline: 1.1237x; 1.1237x over previous
//
#include <hip/hip_runtime.h>
#include <stdint.h>

// Fused attention: q/k/v projections + softmax(QK^T/32 + mask) @ V
// B=4, S=2048, E=1024.
// GEMMs: 256xBN tile, BK=32, ring-4 LDS double-buffer staged 2 tiles ahead
// via global_load_lds(16B), counted vmcnt at tile boundaries (never drain-0
// in steady state), T2 XOR-swizzled LDS, T5 setprio, T1 XCD swizzle.
//
// ws layout (MB offsets):
//   0: qb bf16[4][2048][1024]      16MB
//  16: kb bf16[4][2048][1024]      16MB
//  32: vT bf16[4][1024][2048]      16MB  (v projected transposed)
//  48: Sb bf16[4][2048][2048]      32MB  (scores -> in-place softmax P)
//  80: xq bf16  96: xk bf16  112: xv bf16
// 128/130/132: Wqb/Wkb/Wvb bf16

typedef __attribute__((ext_vector_type(8))) short s8v;    // 8 bf16 bit patterns
typedef __attribute__((ext_vector_type(4))) float f32x4;

__device__ __forceinline__ unsigned short f2b(float f) {
  union { float f; unsigned u; } c; c.f = f;
  unsigned r = c.u + 0x7fffu + ((c.u >> 16) & 1u);   // RNE, no NaN inputs
  return (unsigned short)(r >> 16);
}
__device__ __forceinline__ float b2f(unsigned short s) {
  union { float f; unsigned u; } c; c.u = ((unsigned)s) << 16; return c.f;
}

__device__ __forceinline__ void gload_lds16(const void* gsrc, void* ldst) {
  __builtin_amdgcn_global_load_lds(
      (__attribute__((address_space(1))) unsigned int*)(uintptr_t)gsrc,
      (__attribute__((address_space(3))) unsigned int*)(unsigned)(uintptr_t)ldst,
      16, 0, 0);
}

template <int N> __device__ __forceinline__ void waitvm() {
  if constexpr (N == 4)      asm volatile("s_waitcnt vmcnt(4)" ::: "memory");
  else if constexpr (N == 3) asm volatile("s_waitcnt vmcnt(3)" ::: "memory");
  else                       asm volatile("s_waitcnt vmcnt(0)" ::: "memory");
}

// swizzle: involution on region-relative byte offsets (bits 7..9 -> 4..6).
// ds_read of 16 consecutive rows lands 2-way per bank group (free, m136).
__device__ __forceinline__ int swz(int o) { return o ^ (((o >> 7) & 7) << 4); }

// NT GEMM: C[m][n] = scale * sum_k A[m][k]*B[n][k]  (+ bias / + mask)
// M multiple of 256, N multiple of BN=NFRAG*64, K multiple of 64 (NT>=2).
// BIAS: 0 none, 1 bias[col], 2 bias[row]. MASK: add f32 mask[row][col].
template <int NFRAG, bool OUT_BF16, int BIAS, bool MASK>
__global__ __launch_bounds__(512, 2) void gemm_nt(
    const unsigned short* __restrict__ A, long strideAb, int lda,
    const unsigned short* __restrict__ B, long strideBb, int ldb,
    void* __restrict__ Cptr, long strideCb, int ldc,
    const float* __restrict__ bias,
    const float* __restrict__ maskp, long strideMb, int ldM,
    int K, float scale, int tilesN, int tilesMN) {
  constexpr int BN = NFRAG * 64;
  constexpr int ASLOT = 256 * 64;            // 16 KB (256 rows x 64B)
  constexpr int BSLOT = BN * 64;             // 16/8 KB
  constexpr int SLOT = ASLOT + BSLOT;
  constexpr int CH = SLOT / 1024;            // 1KB chunks per tile
  constexpr int GPW = CH / 8;                // gloads per wave per tile
  static_assert(4 * SLOT <= 160 * 1024, "LDS budget");
  __shared__ __align__(16) char lds[4 * SLOT];

  // T1: bijective XCD swizzle (gridDim.x % 8 == 0 for all our launches)
  const int nwg = gridDim.x;
  int bid = blockIdx.x;
  bid = (bid & 7) * (nwg >> 3) + (bid >> 3);
  const int batch = bid / tilesMN;
  const int tt = bid - batch * tilesMN;
  const int tm = tt / tilesN, tn = tt - tm * tilesN;
  const int brow = tm << 8, bcol = tn * BN;

  const int tid = threadIdx.x;
  const int lane = tid & 63, w = tid >> 6;   // 8 waves: 2M x 4N
  const int wm = w >> 2, wn = w & 3;
  const int fr = lane & 15, fq = lane >> 4;

  // --- staging source precompute: LDS dest is linear; global src is
  // inverse-swizzled so that swizzled ds_reads see logical data (rule #21).
  const unsigned short* gsrc[GPW];
  int ldsdst[GPW];
  {
    const unsigned short* Ab = A + (long)batch * strideAb;
    const unsigned short* Bb = B + (long)batch * strideBb;
#pragma unroll
    for (int i = 0; i < GPW; i++) {
      const int c = w + i * 8;
      const bool isA = (c < 16);
      const int cc = isA ? c : c - 16;
      const int roff = cc * 1024 + lane * 16;       // region-relative linear
      const int logical = swz(roff);
      const int row = logical >> 6, colb = logical & 63;
      gsrc[i] = (isA ? (Ab + (long)(brow + row) * lda)
                     : (Bb + (long)(bcol + row) * ldb)) + (colb >> 1);
      ldsdst[i] = (isA ? 0 : ASLOT) + cc * 1024;    // wave-uniform base
    }
  }

  // --- ds_read offsets (swizzled, tile-invariant; slot base added per tile)
  int offA[8], offB[NFRAG];
#pragma unroll
  for (int mi = 0; mi < 8; mi++)
    offA[mi] = swz((wm * 128 + mi * 16 + fr) * 64 + fq * 16);
#pragma unroll
  for (int ni = 0; ni < NFRAG; ni++)
    offB[ni] = ASLOT + swz((wn * (NFRAG * 16) + ni * 16 + fr) * 64 + fq * 16);

  f32x4 acc[8][NFRAG];
#pragma unroll
  for (int mi = 0; mi < 8; mi++)
#pragma unroll
    for (int ni = 0; ni < NFRAG; ni++) acc[mi][ni] = (f32x4){0.f, 0.f, 0.f, 0.f};

  const int NT = K >> 5;

  auto STAGE = [&](int kt) {
    char* const sb = lds + (kt & 3) * SLOT;
#pragma unroll
    for (int i = 0; i < GPW; i++)
      gload_lds16(gsrc[i] + (long)kt * 32, sb + ldsdst[i]);
  };

  // prologue: stage tiles 0,1; guarantee tile 0 resident block-wide
  STAGE(0);
  STAGE(1);
  waitvm<GPW>();
  __builtin_amdgcn_s_barrier();
  __builtin_amdgcn_sched_barrier(0);

  for (int t = 0; t < NT; ++t) {
    const char* sb = lds + (t & 3) * SLOT;
    if (t + 2 < NT) STAGE(t + 2);            // writes slot (t+2)&3 != t&3

    s8v bf[NFRAG], af[4];
#pragma unroll
    for (int ni = 0; ni < NFRAG; ni++) bf[ni] = *(const s8v*)(sb + offB[ni]);
#pragma unroll
    for (int mi = 0; mi < 4; mi++) af[mi] = *(const s8v*)(sb + offA[mi]);
    __builtin_amdgcn_s_setprio(1);
#pragma unroll
    for (int mi = 0; mi < 4; mi++)
#pragma unroll
      for (int ni = 0; ni < NFRAG; ni++)
        acc[mi][ni] = __builtin_amdgcn_mfma_f32_16x16x32_bf16(
            af[mi], bf[ni], acc[mi][ni], 0, 0, 0);
    __builtin_amdgcn_s_setprio(0);
#pragma unroll
    for (int mi = 0; mi < 4; mi++) af[mi] = *(const s8v*)(sb + offA[4 + mi]);
    __builtin_amdgcn_s_setprio(1);
#pragma unroll
    for (int mi = 0; mi < 4; mi++)
#pragma unroll
      for (int ni = 0; ni < NFRAG; ni++)
        acc[4 + mi][ni] = __builtin_amdgcn_mfma_f32_16x16x32_bf16(
            af[mi], bf[ni], acc[4 + mi][ni], 0, 0, 0);
    __builtin_amdgcn_s_setprio(0);

    if (t + 1 < NT) {                         // tile boundary
      if (t + 2 < NT) waitvm<GPW>();          // counted: next tile's loads
      else            waitvm<0>();            // tail: drain last tile
      __builtin_amdgcn_s_barrier();
      __builtin_amdgcn_sched_barrier(0);
    }
  }

  // epilogue: C/D layout col=lane&15, row=(lane>>4)*4+r  [m89-verified]
  unsigned short* Cb = (unsigned short*)Cptr;
  float* Cf = (float*)Cptr;
  const long cB = (long)batch * strideCb;
  const float* maskB = MASK ? (maskp + (long)batch * strideMb) : nullptr;
#pragma unroll
  for (int mi = 0; mi < 8; mi++) {
#pragma unroll
    for (int ni = 0; ni < NFRAG; ni++) {
      const int col = bcol + wn * (NFRAG * 16) + ni * 16 + fr;
#pragma unroll
      for (int r = 0; r < 4; r++) {
        const int row = brow + wm * 128 + mi * 16 + fq * 4 + r;
        float v = acc[mi][ni][r] * scale;
        if (BIAS == 1) v += bias[col];
        if (BIAS == 2) v += bias[row];
        if (MASK) v += maskB[(long)row * ldM + col];
        if (OUT_BF16) Cb[cB + (long)row * ldc + col] = f2b(v);
        else          Cf[cB + (long)row * ldc + col] = v;
      }
    }
  }
}

// f32 -> bf16 elementwise, 8 elems/thread, grid-stride
__global__ __launch_bounds__(256) void cvt_f32_bf16(
    const float* __restrict__ in, unsigned short* __restrict__ out, long n8) {
  long i = (long)blockIdx.x * blockDim.x + threadIdx.x;
  const long stride = (long)gridDim.x * blockDim.x;
  for (; i < n8; i += stride) {
    const float* p = in + i * 8;
    f32x4 a = *(const f32x4*)p;
    f32x4 b = *(const f32x4*)(p + 4);
    s8v o;
    o[0] = (short)f2b(a[0]); o[1] = (short)f2b(a[1]);
    o[2] = (short)f2b(a[2]); o[3] = (short)f2b(a[3]);
    o[4] = (short)f2b(b[0]); o[5] = (short)f2b(b[1]);
    o[6] = (short)f2b(b[2]); o[7] = (short)f2b(b[3]);
    *(s8v*)(out + i * 8) = o;
  }
}

// in-place row softmax over 2048 bf16 entries; one block (4 waves) per row
__global__ __launch_bounds__(256) void softmax_inplace(unsigned short* __restrict__ S) {
  const long row = blockIdx.x;
  unsigned short* rp = S + row * 2048;
  const int tid = threadIdx.x, lane = tid & 63, wid = tid >> 6;

  s8v vb = *(const s8v*)&rp[tid * 8];
  float x[8];
#pragma unroll
  for (int j = 0; j < 8; j++) x[j] = b2f((unsigned short)vb[j]);

  float m = x[0];
#pragma unroll
  for (int j = 1; j < 8; j++) m = fmaxf(m, x[j]);
#pragma unroll
  for (int off = 32; off > 0; off >>= 1) m = fmaxf(m, __shfl_xor(m, off, 64));

  __shared__ float red[4];
  if (lane == 0) red[wid] = m;
  __syncthreads();
  m = fmaxf(fmaxf(red[0], red[1]), fmaxf(red[2], red[3]));
  __syncthreads();

  float s = 0.f;
#pragma unroll
  for (int j = 0; j < 8; j++) { x[j] = __expf(x[j] - m); s += x[j]; }
#pragma unroll
  for (int off = 32; off > 0; off >>= 1) s += __shfl_xor(s, off, 64);
  if (lane == 0) red[wid] = s;
  __syncthreads();
  s = red[0] + red[1] + red[2] + red[3];
  const float inv = 1.0f / s;

  s8v ob;
#pragma unroll
  for (int j = 0; j < 8; j++) ob[j] = (short)f2b(x[j] * inv);
  *(s8v*)&rp[tid * 8] = ob;
}

extern "C" void kernel_launch(void* const* d_in, const int* in_sizes, int n_in,
                              void* d_out, int out_size, void* d_ws, size_t ws_size,
                              hipStream_t stream) {
  const float* q    = (const float*)d_in[0];
  const float* k    = (const float*)d_in[1];
  const float* v    = (const float*)d_in[2];
  const float* mask = (const float*)d_in[3];
  const float* Wq   = (const float*)d_in[4];
  const float* bq   = (const float*)d_in[5];
  const float* Wk   = (const float*)d_in[6];
  const float* bk   = (const float*)d_in[7];
  const float* Wv   = (const float*)d_in[8];
  const float* bv   = (const float*)d_in[9];
  float* out = (float*)d_out;

  const size_t MB = 1ull << 20;
  if (ws_size < 134 * MB) return;
  char* ws = (char*)d_ws;
  unsigned short* qb  = (unsigned short*)(ws + 0 * MB);
  unsigned short* kb  = (unsigned short*)(ws + 16 * MB);
  unsigned short* vT  = (unsigned short*)(ws + 32 * MB);
  unsigned short* Sb  = (unsigned short*)(ws + 48 * MB);
  unsigned short* xq  = (unsigned short*)(ws + 80 * MB);
  unsigned short* xk  = (unsigned short*)(ws + 96 * MB);
  unsigned short* xv  = (unsigned short*)(ws + 112 * MB);
  unsigned short* Wqb = (unsigned short*)(ws + 128 * MB);
  unsigned short* Wkb = (unsigned short*)(ws + 130 * MB);
  unsigned short* Wvb = (unsigned short*)(ws + 132 * MB);

  const long NX = 4L * 2048 * 1024;
  const long NW = 1024L * 1024;

  cvt_f32_bf16<<<2048, 256, 0, stream>>>(q, xq, NX / 8);
  cvt_f32_bf16<<<2048, 256, 0, stream>>>(k, xk, NX / 8);
  cvt_f32_bf16<<<2048, 256, 0, stream>>>(v, xv, NX / 8);
  cvt_f32_bf16<<<512, 256, 0, stream>>>(Wq, Wqb, NW / 8);
  cvt_f32_bf16<<<512, 256, 0, stream>>>(Wk, Wkb, NW / 8);
  cvt_f32_bf16<<<512, 256, 0, stream>>>(Wv, Wvb, NW / 8);

  // q,k projections: C[s][f] = x[s][e] W[f][e] + b[f]; M=8192 N=1024 K=1024
  // BN=128: tilesM=32, tilesN=8 -> 256 blocks (1/CU)
  gemm_nt<2, true, 1, false><<<dim3(256), 512, 0, stream>>>(
      xq, 0, 1024, Wqb, 0, 1024, (void*)qb, 0, 1024,
      bq, nullptr, 0, 0, 1024, 1.0f, 8, 256);
  gemm_nt<2, true, 1, false><<<dim3(256), 512, 0, stream>>>(
      xk, 0, 1024, Wkb, 0, 1024, (void*)kb, 0, 1024,
      bk, nullptr, 0, 0, 1024, 1.0f, 8, 256);
  // v transposed: vT[f][s] = Wv[f][e] x[s][e] + bv[f]; M=1024 N=2048, b=4
  // BN=128: tilesM=4, tilesN=16 -> 64/batch -> 256 blocks
  gemm_nt<2, true, 2, false><<<dim3(256), 512, 0, stream>>>(
      Wvb, 0, 1024, xv, 2048L * 1024, 1024, (void*)vT, 1024L * 2048, 2048,
      bv, nullptr, 0, 0, 1024, 1.0f, 16, 64);
  // scores: S = (qb.kb^T)/32 + mask; M=N=2048 K=1024, b=4, bf16 out
  // BN=256: tilesM=8, tilesN=8 -> 64/batch -> 256 blocks
  gemm_nt<4, true, 0, true><<<dim3(256), 512, 0, stream>>>(
      qb, 2048L * 1024, 1024, kb, 2048L * 1024, 1024, (void*)Sb, 2048L * 2048, 2048,
      nullptr, mask, 2048L * 2048, 2048, 1024, 0.03125f, 8, 64);
  softmax_inplace<<<8192, 256, 0, stream>>>(Sb);
  // PV: out[q][e] = P[q][kk] vT[e][kk]; M=2048 N=1024 K=2048, b=4, f32 out
  // BN=128: tilesM=8, tilesN=8 -> 64/batch -> 256 blocks
  gemm_nt<2, false, 0, false><<<dim3(256), 512, 0, stream>>>(
      Sb, 2048L * 2048, 2048, vT, 1024L * 2048, 2048, (void*)out, 2048L * 1024, 1024,
      nullptr, nullptr, 0, 0, 2048, 1.0f, 8, 64);
}